// Round 12
// baseline (42.470 us; speedup 1.0000x reference)
//
#include <hip/hip_runtime.h>

#define N_TOT 8192
#define BSZ   4096
#define DIM   256
#define SLAB  (8192 * 64)   // one K-major slab: 8192 rows x 64 bytes (K-chunk of 64)

typedef __attribute__((ext_vector_type(4)))  float f32x4;
typedef __attribute__((ext_vector_type(16))) float f32x16;
typedef __attribute__((ext_vector_type(4)))  int   i32x4;
typedef __attribute__((ext_vector_type(8)))  int   i32x8;

// zb is pre-scaled by sqrt(2*log2(e)) so that acc = 2*log2(e)*sim and
// exp(2*sim) == exp2(acc) with no extra multiplies in the epilogue.
#define PRESCALE 1.69864362f
#define SCALE1   0x7F7F7F7F    // E8M0 exponent 127 = 2^0 = 1.0 in every byte

// ---------------------------------------------------------------------------
// Kernel 1: L2-normalize rows of zi/zj -> fp8 e4m3, K-MAJOR layout:
//   zbK[kt][row][64B]  (kt = k/64, 4 slabs of 512 KB)
// so a fragment load at fixed kt is contiguous across rows (64B row stride).
// Fused positive-pair dots in fp32 (unscaled).
// ---------------------------------------------------------------------------
__global__ __launch_bounds__(256) void norm_kernel(const float* __restrict__ zi,
                                                   const float* __restrict__ zj,
                                                   unsigned char* __restrict__ zbK,
                                                   float* __restrict__ posPart) {
    __shared__ float buf[2][256];
    const int wid  = threadIdx.x >> 6;
    const int lane = threadIdx.x & 63;
    const int pair = blockIdx.x * 2 + (wid & 1);    // 0..4095
    const bool isZj = (wid >= 2);
    const float* src = isZj ? (zj + (size_t)pair * DIM) : (zi + (size_t)pair * DIM);
    float4 v = ((const float4*)src)[lane];
    float ss = v.x * v.x + v.y * v.y + v.z * v.z + v.w * v.w;
    #pragma unroll
    for (int off = 1; off < 64; off <<= 1) ss += __shfl_xor(ss, off);
    float inv = 1.0f / fmaxf(sqrtf(ss), 1e-12f);
    float4 nv = make_float4(v.x * inv, v.y * inv, v.z * inv, v.w * inv);

    const int outRow = isZj ? (pair + BSZ) : pair;
    int pk = __builtin_amdgcn_cvt_pk_fp8_f32(nv.x * PRESCALE, nv.y * PRESCALE, 0, false);
    pk     = __builtin_amdgcn_cvt_pk_fp8_f32(nv.z * PRESCALE, nv.w * PRESCALE, pk, true);
    // lane covers k = 4*lane..+4 -> slab = lane>>4, byte-in-row = (lane&15)*4
    *(int*)(zbK + (size_t)(lane >> 4) * SLAB + (size_t)outRow * 64 + (lane & 15) * 4) = pk;

    if (!isZj) ((float4*)&buf[wid & 1][0])[lane] = nv;
    __syncthreads();
    if (isZj) {
        float4 a = ((float4*)&buf[wid & 1][0])[lane];
        float d = a.x * nv.x + a.y * nv.y + a.z * nv.z + a.w * nv.w;
        #pragma unroll
        for (int off = 1; off < 64; off <<= 1) d += __shfl_xor(d, off);
        if (lane == 0) posPart[pair] = d;
    }
}

// ---------------------------------------------------------------------------
// Kernel 2: symmetric fused Z*Z^T -> exp2 -> partial row AND col sums.
// ZERO BARRIERS, ZERO K-LOOP LDS: 2080 upper-tri 128x128 jobs; each block's
// 4 waves are independent quadrants (wr,wc) computing 64x64 via 2x2 of
// mfma_scale_f32_32x32x64_f8f6f4 (unit scales). All A (16) and B (16)
// fragments are loaded DIRECTLY from the K-major zbK with fully-coalesced
// dwordx4 (64 lanes x 16B in a contiguous 2KB window) — the fix for round
// 10's transaction blowup. Compiler schedules loads/waitcnts; quadrant
// waves sharing A/B halves get L1 reuse.
// Frag (r9-validated): lane (r31,hi) = row r31, k = hi*32..+32, two dwordx4.
// C/D (m74/m101): col = lane&31, row = (reg&3)+8*(reg>>2)+4*(lane>>5).
// Slots: row-sums -> bj*2+wc; col-sums -> bi*2+wr (skip if diag).
// ---------------------------------------------------------------------------
__global__ __launch_bounds__(256, 2) void sim_kernel(const unsigned char* __restrict__ zbK,
                                                     float* __restrict__ partial) {
    __shared__ float swAll[4][2048];   // per-wave [64][32] f32 transpose scratch

    const int t    = threadIdx.x;
    const int lane = t & 63;
    const int wid  = t >> 6;
    const int wr   = wid >> 1;     // 0..1
    const int wc   = wid & 1;      // 0..1
    const int hi   = lane >> 5;    // 0..1
    const int r31  = lane & 31;

    // decode upper-triangular (bi, bj), bi <= bj (r9-validated)
    const int k = blockIdx.x;                       // 0..2079
    int bi = (int)((129.0f - sqrtf(16641.0f - 8.0f * (float)k)) * 0.5f);
    while (bi * 64 - bi * (bi - 1) / 2 > k) bi--;
    while ((bi + 1) * 64 - (bi + 1) * bi / 2 <= k) bi++;
    const int bj = bi + (k - (bi * 64 - bi * (bi - 1) / 2));
    const bool diag = (bi == bj);

    const int row0 = bi * 128;
    const int col0 = bj * 128;

    f32x16 acc[2][2];
    #pragma unroll
    for (int mt = 0; mt < 2; mt++)
        #pragma unroll
        for (int nt = 0; nt < 2; nt++)
            #pragma unroll
            for (int r = 0; r < 16; r++) acc[mt][nt][r] = 0.f;

    // ---- direct fragment loads (all of K upfront; compiler-scheduled) ----
    i32x4 aL[2][4], aH[2][4], bL[2][4], bH[2][4];   // [mt|nt][kt]
    #pragma unroll
    for (int mt = 0; mt < 2; mt++) {
        const size_t ra = (size_t)(row0 + wr * 64 + mt * 32 + r31) * 64 + hi * 32;
        const size_t rb = (size_t)(col0 + wc * 64 + mt * 32 + r31) * 64 + hi * 32;
        #pragma unroll
        for (int kt = 0; kt < 4; kt++) {
            const unsigned char* pa = zbK + (size_t)kt * SLAB + ra;
            const unsigned char* pb = zbK + (size_t)kt * SLAB + rb;
            aL[mt][kt] = *(const i32x4*)pa;
            aH[mt][kt] = *(const i32x4*)(pa + 16);
            bL[mt][kt] = *(const i32x4*)pb;
            bH[mt][kt] = *(const i32x4*)(pb + 16);
        }
    }

    // ---- 16 MX MFMAs (4 independent acc chains of 4) ----
    #pragma unroll
    for (int kt = 0; kt < 4; kt++) {
        #pragma unroll
        for (int mt = 0; mt < 2; mt++) {
            const i32x8 a = __builtin_shufflevector(aL[mt][kt], aH[mt][kt],
                                                    0, 1, 2, 3, 4, 5, 6, 7);
            #pragma unroll
            for (int nt = 0; nt < 2; nt++) {
                const i32x8 b = __builtin_shufflevector(bL[nt][kt], bH[nt][kt],
                                                        0, 1, 2, 3, 4, 5, 6, 7);
                acc[mt][nt] = __builtin_amdgcn_mfma_scale_f32_32x32x64_f8f6f4(
                    a, b, acc[mt][nt], 0, 0, 0, SCALE1, 0, SCALE1);
            }
        }
    }

    // ---- epilogue (32x32 C/D layout, r9-validated): exp2; row+col sums ----
    float* sw = swAll[wid];
    float csum[2] = {0.f, 0.f};

    #pragma unroll
    for (int mt = 0; mt < 2; mt++) {
        #pragma unroll
        for (int reg = 0; reg < 16; reg++) {
            const int row_l = mt * 32 + (reg & 3) + ((reg >> 2) << 3) + (hi << 2);
            const int rowg  = row0 + wr * 64 + row_l;
            float r = 0.f;
            #pragma unroll
            for (int nt = 0; nt < 2; nt++) {
                float e = exp2f(acc[mt][nt][reg]);
                if (diag && rowg == (col0 + wc * 64 + nt * 32 + r31)) e = 0.0f;
                r += e;
                csum[nt] += e;
            }
            sw[row_l * 32 + ((((r31 >> 2) ^ (row_l & 7))) << 2) + (r31 & 3)] = r;
        }
    }

    // col sums: combine hi-halves; lane stores col = lane of this quadrant.
    if (!diag) {
        float cv0 = csum[0] + __shfl_xor(csum[0], 32);
        float cv1 = csum[1] + __shfl_xor(csum[1], 32);
        const float cv = hi ? cv1 : cv0;
        partial[(size_t)(bi * 2 + wr) * N_TOT + col0 + wc * 64 + lane] = cv;
    }

    // row sums: read back this lane's row (wave-private scratch), store.
    asm volatile("s_waitcnt lgkmcnt(0)" ::: "memory");
    __builtin_amdgcn_sched_barrier(0);
    float tot = 0.f;
    #pragma unroll
    for (int q = 0; q < 8; q++) {
        const int ch = q ^ (lane & 7);
        f32x4 v = *(const f32x4*)(sw + lane * 32 + ch * 4);
        tot += v[0] + v[1] + v[2] + v[3];
    }
    partial[(size_t)(bj * 2 + wc) * N_TOT + row0 + wr * 64 + lane] = tot;
}

// ---------------------------------------------------------------------------
// Kernel 3: per-row sum of 128 partials -> log(negsum+eps). Grid 128 blocks,
// each block = 64 rows; wave w sums slots [w*32, w*32+32).
// ---------------------------------------------------------------------------
__global__ __launch_bounds__(256) void rowlog_kernel(const float* __restrict__ partial,
                                                     float* __restrict__ logPart) {
    const int lane = threadIdx.x & 63;
    const int w    = threadIdx.x >> 6;
    const int row  = blockIdx.x * 64 + lane;
    float s = 0.f;
    #pragma unroll 8
    for (int p = w * 32; p < w * 32 + 32; p++) s += partial[(size_t)p * N_TOT + row];
    __shared__ float red[4][64];
    red[w][lane] = s;
    __syncthreads();
    if (w == 0) {
        float tot = red[0][lane] + red[1][lane] + red[2][lane] + red[3][lane];
        float v = logf(tot + 1e-8f);
        #pragma unroll
        for (int off = 1; off < 64; off <<= 1) v += __shfl_xor(v, off);
        if (lane == 0) logPart[blockIdx.x] = v;
    }
}

// ---------------------------------------------------------------------------
// Kernel 4: final scalar: loss = mean(log terms) - 2*sum(dots)/BSZ
// ---------------------------------------------------------------------------
__global__ __launch_bounds__(256) void final_kernel(const float* __restrict__ logPart,
                                                    const float* __restrict__ posPart,
                                                    float* __restrict__ out) {
    const int t = threadIdx.x;
    float ps = 0.f;
    for (int i = t; i < BSZ; i += 256) ps += posPart[i];
    float ls = (t < 128) ? logPart[t] : 0.f;
    #pragma unroll
    for (int off = 1; off < 64; off <<= 1) {
        ps += __shfl_xor(ps, off);
        ls += __shfl_xor(ls, off);
    }
    __shared__ float redp[4], redl[4];
    const int lane = t & 63, wid = t >> 6;
    if (lane == 0) { redp[wid] = ps; redl[wid] = ls; }
    __syncthreads();
    if (t == 0) {
        const float posSum = redp[0] + redp[1] + redp[2] + redp[3];
        const float logSum = redl[0] + redl[1] + redl[2] + redl[3];
        out[0] = logSum / (float)N_TOT - 2.0f * posSum / (float)BSZ;
    }
}

extern "C" void kernel_launch(void* const* d_in, const int* in_sizes, int n_in,
                              void* d_out, int out_size, void* d_ws, size_t ws_size,
                              hipStream_t stream) {
    const float* zi = (const float*)d_in[0];
    const float* zj = (const float*)d_in[1];
    float* out = (float*)d_out;

    char* ws = (char*)d_ws;
    unsigned char* zbK = (unsigned char*)ws;                     // 4 slabs = 2 MB
    float* partial     = (float*)(ws + (size_t)(4 << 20));       // 128*8192*4 = 4 MB
    float* logPart     = (float*)(ws + (size_t)(8 << 20));       // 128 floats
    float* posPart     = (float*)(ws + (size_t)(8 << 20) + 4096);// 4096 floats

    norm_kernel<<<2048, 256, 0, stream>>>(zi, zj, zbK, posPart);
    sim_kernel<<<2080, 256, 0, stream>>>(zbK, partial);
    rowlog_kernel<<<128, 256, 0, stream>>>(partial, logPart);
    final_kernel<<<1, 256, 0, stream>>>(logPart, posPart, out);
}